// Round 2
// baseline (677.749 us; speedup 1.0000x reference)
//
#include <hip/hip_runtime.h>

#define NB 10
#define NCOPY 32          // replicated LDS histograms (one per lane%32)
#define PAD 33            // 30 slots padded to 33 (odd stride -> copies spread over banks)
#define NSLOT 30          // {count, sum_conf, sum_pos} x 10 bins

__global__ void rd_zero_ws(float* __restrict__ ws) {
    int t = threadIdx.x;
    if (t < NSLOT) ws[t] = 0.0f;
}

__device__ __forceinline__ void rd_acc(float x, int lab, float* __restrict__ h) {
    // sigmoid(x) = 1 / (1 + exp(-x))
    float e = __expf(-x);
    float conf = 1.0f / (1.0f + e);
    // bin = clip(ceil(conf*10)-1, 0, 9)
    int b = (int)ceilf(conf * 10.0f) - 1;
    b = min(NB - 1, max(0, b));
    float* slot = h + b * 3;
    atomicAdd(slot + 0, 1.0f);
    atomicAdd(slot + 1, conf);
    atomicAdd(slot + 2, (float)lab);
}

__global__ __launch_bounds__(256) void rd_hist(const float* __restrict__ logits,
                                               const int* __restrict__ labels,
                                               float* __restrict__ ws,
                                               long long n) {
    __shared__ float hist[NCOPY * PAD];
    for (int i = threadIdx.x; i < NCOPY * PAD; i += blockDim.x) hist[i] = 0.0f;
    __syncthreads();

    float* h = &hist[(threadIdx.x & 31) * PAD];

    long long tid    = (long long)blockIdx.x * blockDim.x + threadIdx.x;
    long long stride = (long long)gridDim.x * blockDim.x;
    long long n4     = n >> 2;

    const float4* l4 = (const float4*)logits;
    const int4*   b4 = (const int4*)labels;

    for (long long i = tid; i < n4; i += stride) {
        float4 x = l4[i];
        int4   y = b4[i];
        rd_acc(x.x, y.x, h);
        rd_acc(x.y, y.y, h);
        rd_acc(x.z, y.z, h);
        rd_acc(x.w, y.w, h);
    }
    // scalar tail (empty for N=2^25, kept for generality)
    for (long long i = (n4 << 2) + tid; i < n; i += stride) {
        rd_acc(logits[i], labels[i], h);
    }

    __syncthreads();

    // reduce 32 copies -> 30 slots, one global atomic per slot per block
    for (int t = threadIdx.x; t < NSLOT; t += blockDim.x) {
        float s = 0.0f;
        #pragma unroll
        for (int c = 0; c < NCOPY; ++c) s += hist[c * PAD + t];
        atomicAdd(&ws[t], s);
    }
}

__global__ void rd_finalize(const float* __restrict__ ws, float* __restrict__ out) {
    int b = threadIdx.x;
    if (b < NB) {
        float cnt = ws[b * 3 + 0];
        float sc  = ws[b * 3 + 1];
        float sp  = ws[b * 3 + 2];
        float denom = fmaxf(cnt, 1.0f);
        float pos = (cnt > 0.0f) ? (sp / denom) : 0.0f;
        float cf  = (cnt > 0.0f) ? (sc / denom) : 0.0f;
        out[b]      = pos;   // positives_per_bin
        out[NB + b] = cf;    // confidence_per_bin
    }
}

extern "C" void kernel_launch(void* const* d_in, const int* in_sizes, int n_in,
                              void* d_out, int out_size, void* d_ws, size_t ws_size,
                              hipStream_t stream) {
    const float* logits = (const float*)d_in[0];
    const int*   labels = (const int*)d_in[1];
    float* out = (float*)d_out;
    float* ws  = (float*)d_ws;
    long long n = (long long)in_sizes[0];

    rd_zero_ws<<<1, 64, 0, stream>>>(ws);

    // 2048 blocks x 256 threads = 2^19 threads; 16 float4 iterations each at N=2^25
    rd_hist<<<2048, 256, 0, stream>>>(logits, labels, ws, n);

    rd_finalize<<<1, 64, 0, stream>>>(ws, out);
}

// Round 3
// 323.953 us; speedup vs baseline: 2.0921x; 2.0921x over previous
//
#include <hip/hip_runtime.h>

#define NB 10
#define NCOPY 32            // replicated LDS histograms, copy = lane & 31
#define SLOTS 20            // [0..9] packed (count | pos<<16), [10..19] conf fixed-point
#define PAD 21              // odd stride -> copies land on distinct banks
#define CONF_SCALE 65536.0f

typedef unsigned int u32;
typedef unsigned long long u64;

// ws layout: u64 conf_fx[10] @0 (80B) | u32 cnt[10] @80 | u32 pos[10] @120  => 160B
__global__ void rd_zero_ws(u32* __restrict__ ws) {
    int t = threadIdx.x;
    if (t < 40) ws[t] = 0u;
}

__device__ __forceinline__ void rd_acc(float x, int lab, u32* __restrict__ h) {
    float e = __expf(-x);
    float conf = __builtin_amdgcn_rcpf(1.0f + e);      // sigmoid, ~1 ulp
    int b = (int)ceilf(conf * 10.0f) - 1;              // bins are (l, u]
    b = min(NB - 1, max(0, b));
    u32 packed = 1u | ((u32)lab << 16);                // count low16, pos high16
    u32 cfx = (u32)(conf * CONF_SCALE + 0.5f);
    atomicAdd(&h[b], packed);                          // native ds_add_u32
    atomicAdd(&h[NB + b], cfx);                        // native ds_add_u32
}

__global__ __launch_bounds__(256) void rd_hist(const float* __restrict__ logits,
                                               const int* __restrict__ labels,
                                               u32* __restrict__ ws,
                                               long long n) {
    __shared__ u32 hist[NCOPY * PAD];
    for (int i = threadIdx.x; i < NCOPY * PAD; i += blockDim.x) hist[i] = 0u;
    __syncthreads();

    u32* h = &hist[(threadIdx.x & 31) * PAD];

    long long tid    = (long long)blockIdx.x * blockDim.x + threadIdx.x;
    long long stride = (long long)gridDim.x * blockDim.x;
    long long n4     = n >> 2;

    const float4* l4 = (const float4*)logits;
    const int4*   b4 = (const int4*)labels;

    for (long long i = tid; i < n4; i += stride) {
        float4 x = l4[i];
        int4   y = b4[i];
        rd_acc(x.x, y.x, h);
        rd_acc(x.y, y.y, h);
        rd_acc(x.z, y.z, h);
        rd_acc(x.w, y.w, h);
    }
    for (long long i = (n4 << 2) + tid; i < n; i += stride) {  // tail (empty at N=2^25)
        rd_acc(logits[i], labels[i], h);
    }

    __syncthreads();

    // reduce 32 copies -> 20 slots; native integer global atomics only
    int t = threadIdx.x;
    if (t < SLOTS) {
        u32 s = 0;
        #pragma unroll
        for (int c = 0; c < NCOPY; ++c) s += hist[c * PAD + t];
        u64* conf64 = (u64*)ws;
        u32* cnt    = ws + 20;   // byte offset 80
        u32* pos    = ws + 30;   // byte offset 120
        if (t < NB) {
            atomicAdd(&cnt[t], s & 0xFFFFu);
            atomicAdd(&pos[t], s >> 16);
        } else {
            atomicAdd(&conf64[t - NB], (u64)s);   // native global_atomic_add_x2
        }
    }
}

__global__ void rd_finalize(const u32* __restrict__ ws, float* __restrict__ out) {
    int b = threadIdx.x;
    if (b < NB) {
        const u64* conf64 = (const u64*)ws;
        float cnt = (float)ws[20 + b];
        float sp  = (float)ws[30 + b];
        float sc  = (float)((double)conf64[b] * (1.0 / 65536.0));
        float denom = fmaxf(cnt, 1.0f);
        bool ne = cnt > 0.0f;
        out[b]      = ne ? (sp / denom) : 0.0f;   // positives_per_bin
        out[NB + b] = ne ? (sc / denom) : 0.0f;   // confidence_per_bin
    }
}

extern "C" void kernel_launch(void* const* d_in, const int* in_sizes, int n_in,
                              void* d_out, int out_size, void* d_ws, size_t ws_size,
                              hipStream_t stream) {
    const float* logits = (const float*)d_in[0];
    const int*   labels = (const int*)d_in[1];
    float* out = (float*)d_out;
    u32*   ws  = (u32*)d_ws;
    long long n = (long long)in_sizes[0];

    rd_zero_ws<<<1, 64, 0, stream>>>(ws);
    // 2048 blocks x 256 threads: 64 elements/thread, 16 float4 iterations
    rd_hist<<<2048, 256, 0, stream>>>(logits, labels, ws, n);
    rd_finalize<<<1, 64, 0, stream>>>(ws, out);
}